// Round 17
// baseline (148.806 us; speedup 1.0000x reference)
//
#include <hip/hip_runtime.h>

#define B 128
#define N 65536
#define D 512
#define K 5
#define M 256              // D * RATIO
#define GPB 128            // gallery rows per block (kernel1)
#define NBLK1 (N / GPB)    // 512 blocks
#define CHG 16             // g rows per chunk
#define NCHK (GPB / CHG)   // 8

typedef __attribute__((ext_vector_type(8))) short short8;
typedef __attribute__((ext_vector_type(4))) float f32x4;

// pack two fp32 -> one u32 of 2 bf16 (truncation) via v_perm_b32.
__device__ __forceinline__ unsigned int pack_bf2(float lo, float hi) {
    return __builtin_amdgcn_perm(__float_as_uint(hi), __float_as_uint(lo), 0x07060302u);
}

__device__ __forceinline__ void top5_insert(float v, int gi, float tv[K], int ti[K]) {
    // descending by value, ties broken by lower index (matches lax.top_k)
    if (v > tv[K - 1] || (v == tv[K - 1] && gi < ti[K - 1])) {
        tv[K - 1] = v; ti[K - 1] = gi;
        #pragma unroll
        for (int k = K - 1; k > 0; --k) {
            bool sw = (tv[k] > tv[k - 1]) || (tv[k] == tv[k - 1] && ti[k] < ti[k - 1]);
            if (sw) {
                float fv = tv[k]; tv[k] = tv[k - 1]; tv[k - 1] = fv;
                int fi = ti[k]; ti[k] = ti[k - 1]; ti[k - 1] = fi;
            }
        }
    }
}

// k0t: t_f (128x512 fp32) -> bf16 once. L2-resident thereafter.
__global__ __launch_bounds__(256) void k0_cvt_t(const float* __restrict__ t_f,
                                                unsigned int* __restrict__ t_bf) {
    int i = blockIdx.x * 256 + threadIdx.x;   // float4 index, 16384 total
    float4 v = reinterpret_cast<const float4*>(t_f)[i];
    uint2 p;
    p.x = pack_bf2(v.x, v.y);
    p.y = pack_bf2(v.z, v.w);
    reinterpret_cast<uint2*>(t_bf)[i] = p;
}

// k1 (R7's proven ~40us kernel, verbatim): 512 thr / 8 waves, 33KB LDS ->
// 4 blocks/CU = 32 waves/CU of INDEPENDENT streaming (the occupancy that
// every 1-block/CU DMA variant lacked). Wave w owns g-rows {2w,2w+1} fully:
// every global load is a contiguous 1KB wave instruction. Named depth-2
// register prefetch, bf16 LDS staging with XOR swizzle, one barrier/chunk.
__global__ __launch_bounds__(512) void k1_sims(const unsigned short* __restrict__ t_bf,
                                               const float* __restrict__ gal,
                                               float2* __restrict__ partial) {
    __shared__ __align__(16) unsigned short gLds[2][CHG * D];
    __shared__ float normP[2][CHG];

    const int tid = threadIdx.x;
    const int blk = (blockIdx.x & 7) * (NBLK1 / 8) + (blockIdx.x >> 3);  // XCD swizzle
    const int lane = tid & 63;
    const int w = tid >> 6;
    const int l15 = lane & 15;
    const int l4 = lane >> 4;
    const int bh = lane >> 3;
    const int colb = (lane & 7) * 8;
    const int xr = bh << 4;
    const int rb = l15 * 64 + l4 * 16;

    short8 afr[16];
    {
        const unsigned short* tp = t_bf + (size_t)(w * 16 + l15) * D + l4 * 8;
        #pragma unroll
        for (int ks = 0; ks < 16; ++ks) {
            uint4 q = *reinterpret_cast<const uint4*>(tp + ks * 32);
            asm volatile("" : "+v"(q.x), "+v"(q.y), "+v"(q.z), "+v"(q.w));
            afr[ks] = *reinterpret_cast<short8*>(&q);
        }
    }

    float lst[4][K];
    #pragma unroll
    for (int r = 0; r < 4; ++r)
        #pragma unroll
        for (int k = 0; k < K; ++k) lst[r][k] = -1e30f;

    const float* gbase = gal + ((size_t)blk * GPB + 2 * w) * D + lane * 4;

#define LOADSET(R0, R1, R2, R3, CIDX) do { \
        const float* gp_ = gbase + (size_t)(CIDX) * (CHG * D); \
        R0 = *reinterpret_cast<const float4*>(gp_); \
        R1 = *reinterpret_cast<const float4*>(gp_ + 256); \
        R2 = *reinterpret_cast<const float4*>(gp_ + 512); \
        R3 = *reinterpret_cast<const float4*>(gp_ + 768); \
    } while (0)

#define STAGE(R0, R1, R2, R3, BUFI) do { \
        char* LB_ = reinterpret_cast<char*>(&gLds[BUFI][0]); \
        uint2 q_; \
        q_.x = pack_bf2(R0.x, R0.y); q_.y = pack_bf2(R0.z, R0.w); \
        *reinterpret_cast<uint2*>(LB_ + (bh)      * 1024 + (((2 * w) * 64 + colb) ^ xr)) = q_; \
        q_.x = pack_bf2(R1.x, R1.y); q_.y = pack_bf2(R1.z, R1.w); \
        *reinterpret_cast<uint2*>(LB_ + (8 + bh)  * 1024 + (((2 * w) * 64 + colb) ^ xr)) = q_; \
        q_.x = pack_bf2(R2.x, R2.y); q_.y = pack_bf2(R2.z, R2.w); \
        *reinterpret_cast<uint2*>(LB_ + (bh)      * 1024 + (((2 * w + 1) * 64 + colb) ^ xr)) = q_; \
        q_.x = pack_bf2(R3.x, R3.y); q_.y = pack_bf2(R3.z, R3.w); \
        *reinterpret_cast<uint2*>(LB_ + (8 + bh)  * 1024 + (((2 * w + 1) * 64 + colb) ^ xr)) = q_; \
        float nrA_ = 0.f, nrB_ = 0.f; \
        nrA_ = fmaf(R0.x, R0.x, nrA_); nrA_ = fmaf(R0.y, R0.y, nrA_); \
        nrA_ = fmaf(R0.z, R0.z, nrA_); nrA_ = fmaf(R0.w, R0.w, nrA_); \
        nrA_ = fmaf(R1.x, R1.x, nrA_); nrA_ = fmaf(R1.y, R1.y, nrA_); \
        nrA_ = fmaf(R1.z, R1.z, nrA_); nrA_ = fmaf(R1.w, R1.w, nrA_); \
        nrB_ = fmaf(R2.x, R2.x, nrB_); nrB_ = fmaf(R2.y, R2.y, nrB_); \
        nrB_ = fmaf(R2.z, R2.z, nrB_); nrB_ = fmaf(R2.w, R2.w, nrB_); \
        nrB_ = fmaf(R3.x, R3.x, nrB_); nrB_ = fmaf(R3.y, R3.y, nrB_); \
        nrB_ = fmaf(R3.z, R3.z, nrB_); nrB_ = fmaf(R3.w, R3.w, nrB_); \
        _Pragma("unroll") \
        for (int s_ = 1; s_ < 64; s_ <<= 1) { \
            nrA_ += __shfl_xor(nrA_, s_); \
            nrB_ += __shfl_xor(nrB_, s_); \
        } \
        if (lane == 0) { normP[BUFI][2 * w] = nrA_; normP[BUFI][2 * w + 1] = nrB_; } \
    } while (0)

#define COMPUTE(BUFI, CIDX) do { \
        f32x4 acc0_ = (f32x4)0.f, acc1_ = (f32x4)0.f; \
        const char* LB_ = reinterpret_cast<const char*>(&gLds[BUFI][0]); \
        _Pragma("unroll") \
        for (int ks_ = 0; ks_ < 16; ks_ += 2) { \
            short8 b0_ = *reinterpret_cast<const short8*>(LB_ + ks_ * 1024 + (rb ^ ((ks_ & 7) << 4))); \
            short8 b1_ = *reinterpret_cast<const short8*>(LB_ + (ks_ + 1) * 1024 + (rb ^ (((ks_ + 1) & 7) << 4))); \
            acc0_ = __builtin_amdgcn_mfma_f32_16x16x32_bf16(afr[ks_], b0_, acc0_, 0, 0, 0); \
            acc1_ = __builtin_amdgcn_mfma_f32_16x16x32_bf16(afr[ks_ + 1], b1_, acc1_, 0, 0, 0); \
        } \
        float sc_ = rsqrtf(normP[BUFI][l15]); \
        unsigned meta_ = (unsigned)((CIDX) * CHG + l15); \
        _Pragma("unroll") \
        for (int r_ = 0; r_ < 4; ++r_) { \
            float s_ = (acc0_[r_] + acc1_[r_]) * sc_; \
            float sp_ = __uint_as_float((__float_as_uint(s_) & 0xFFFFFF00u) | meta_); \
            if (sp_ > lst[r_][K - 1]) { \
                lst[r_][K - 1] = sp_; \
                _Pragma("unroll") \
                for (int k_ = K - 1; k_ > 0; --k_) \
                    if (lst[r_][k_] > lst[r_][k_ - 1]) { \
                        float t_ = lst[r_][k_]; lst[r_][k_] = lst[r_][k_ - 1]; lst[r_][k_ - 1] = t_; \
                    } \
            } \
        } \
    } while (0)

    float4 A0, A1, A2, A3, B0, B1, B2, B3;
    LOADSET(A0, A1, A2, A3, 0);
    LOADSET(B0, B1, B2, B3, 1);
    STAGE(A0, A1, A2, A3, 0);
    __syncthreads();

    #pragma unroll
    for (int cc = 0; cc < NCHK; cc += 2) {
        if (cc + 2 < NCHK) LOADSET(A0, A1, A2, A3, cc + 2);
        if (cc + 1 < NCHK) STAGE(B0, B1, B2, B3, 1);
        COMPUTE(0, cc);
        __syncthreads();
        if (cc + 3 < NCHK) LOADSET(B0, B1, B2, B3, cc + 3);
        if (cc + 2 < NCHK) STAGE(A0, A1, A2, A3, 0);
        COMPUTE(1, cc + 1);
        __syncthreads();
    }

    #pragma unroll
    for (int mk = 1; mk <= 8; mk <<= 1) {
        #pragma unroll
        for (int r = 0; r < 4; ++r) {
            float inc[K];
            #pragma unroll
            for (int k = 0; k < K; ++k) inc[k] = __shfl_xor(lst[r][k], mk);
            #pragma unroll
            for (int k = 0; k < K; ++k) {
                if (inc[k] > lst[r][K - 1]) {
                    lst[r][K - 1] = inc[k];
                    #pragma unroll
                    for (int q = K - 1; q > 0; --q)
                        if (lst[r][q] > lst[r][q - 1]) {
                            float t2 = lst[r][q]; lst[r][q] = lst[r][q - 1]; lst[r][q - 1] = t2;
                        }
                }
            }
        }
    }

    #pragma unroll
    for (int rr = 0; rr < 4; ++rr) {
        if (l15 == rr) {
            int b = w * 16 + l4 * 4 + rr;
            #pragma unroll
            for (int k = 0; k < K; ++k) {
                unsigned sp = __float_as_uint(lst[rr][k]);
                int g = blk * GPB + (int)(sp & 0xFFu);
                partial[((size_t)b * NBLK1 + blk) * K + k] = make_float2(lst[rr][k], __int_as_float(g));
            }
        }
    }
#undef LOADSET
#undef STAGE
#undef COMPUTE
}

// k2: merge 512 partial top-5 lists per batch row -> top_idx. Shuffle-first:
// 6 shfl_xor levels per wave, then one LDS merge of the 8 wave lists.
__global__ __launch_bounds__(512) void k2_merge(const float2* __restrict__ partial,
                                                int* __restrict__ top_idx) {
    __shared__ float2 wlist[8][K];
    const int b = blockIdx.x;
    const int p = threadIdx.x;
    const int lane = p & 63;
    const int w = p >> 6;

    float mv[K]; int mi[K];
    #pragma unroll
    for (int k = 0; k < K; ++k) {
        float2 c = partial[((size_t)b * NBLK1 + p) * K + k];
        mv[k] = c.x; mi[k] = __float_as_int(c.y);
    }
    #pragma unroll
    for (int mk = 1; mk <= 32; mk <<= 1) {
        float ov[K]; int oi[K];
        #pragma unroll
        for (int k = 0; k < K; ++k) { ov[k] = __shfl_xor(mv[k], mk); oi[k] = __shfl_xor(mi[k], mk); }
        #pragma unroll
        for (int k = 0; k < K; ++k) top5_insert(ov[k], oi[k], mv, mi);
    }
    if (lane == 0) {
        #pragma unroll
        for (int k = 0; k < K; ++k) wlist[w][k] = make_float2(mv[k], __int_as_float(mi[k]));
    }
    __syncthreads();
    if (w == 0) {
        #pragma unroll
        for (int k = 0; k < K; ++k) { mv[k] = -1e30f; mi[k] = 0x7fffffff; }
        if (lane < 8) {
            #pragma unroll
            for (int k = 0; k < K; ++k) {
                float2 c = wlist[lane][k];
                mv[k] = c.x; mi[k] = __float_as_int(c.y);
            }
        }
        #pragma unroll
        for (int mk = 1; mk <= 4; mk <<= 1) {
            float ov[K]; int oi[K];
            #pragma unroll
            for (int k = 0; k < K; ++k) { ov[k] = __shfl_xor(mv[k], mk); oi[k] = __shfl_xor(mi[k], mk); }
            #pragma unroll
            for (int k = 0; k < K; ++k) top5_insert(ov[k], oi[k], mv, mi);
        }
        if (lane == 0) {
            #pragma unroll
            for (int k = 0; k < K; ++k) top_idx[b * K + k] = mi[k];
        }
    }
}

// k3: one block per (b,k) row: bottom-m membership of |gal[row,c]*s_f[b,c]|
// (per-row norms are positive constants -> ordering matches the reference's
// normalized products). Plain stores; kernel-boundary coherence (R8 lesson).
__global__ __launch_bounds__(512) void k3_member(const float* __restrict__ s_f,
                                                 const float* __restrict__ gal,
                                                 const int* __restrict__ top_idx,
                                                 unsigned long long* __restrict__ bkmask) {
    __shared__ __align__(16) float pS[D];
    const int p = threadIdx.x;
    const int bk = blockIdx.x;
    const int b = bk / K;
    const int row = top_idx[bk];
    float pv = fabsf(gal[(size_t)row * D + p] * s_f[(size_t)b * D + p]);
    pS[p] = pv;
    __syncthreads();
    int cnt = 0;
    const float4* p4 = reinterpret_cast<const float4*>(pS);
    #pragma unroll 4
    for (int j = 0; j < D / 4; ++j) {
        float4 o = p4[j];
        cnt += (o.x < pv || (o.x == pv && (4 * j + 0) < p)) ? 1 : 0;
        cnt += (o.y < pv || (o.y == pv && (4 * j + 1) < p)) ? 1 : 0;
        cnt += (o.z < pv || (o.z == pv && (4 * j + 2) < p)) ? 1 : 0;
        cnt += (o.w < pv || (o.w == pv && (4 * j + 3) < p)) ? 1 : 0;
    }
    unsigned long long bm = __ballot(cnt < M);
    if ((p & 63) == 0) bkmask[(size_t)bk * 8 + (p >> 6)] = bm;
}

// k4: AND-reduce the 640 per-(b,k) masks, emit the output mask. 40 KB, L2-hot.
__global__ __launch_bounds__(512) void k4_final(const unsigned long long* __restrict__ bkmask,
                                                float* __restrict__ out) {
    const int c = threadIdx.x;
    const int word = c >> 6, bit = c & 63;
    unsigned long long acc = ~0ull;
    for (int bk = 0; bk < B * K; bk += 4) {
        acc &= bkmask[(size_t)bk * 8 + word];
        acc &= bkmask[(size_t)(bk + 1) * 8 + word];
        acc &= bkmask[(size_t)(bk + 2) * 8 + word];
        acc &= bkmask[(size_t)(bk + 3) * 8 + word];
    }
    out[c] = ((acc >> bit) & 1ull) ? 0.0f : 1.0f;
}

extern "C" void kernel_launch(void* const* d_in, const int* in_sizes, int n_in,
                              void* d_out, int out_size, void* d_ws, size_t ws_size,
                              hipStream_t stream) {
    (void)in_sizes; (void)n_in; (void)out_size; (void)ws_size;
    const float* s_f = (const float*)d_in[0];
    const float* t_f = (const float*)d_in[1];
    const float* gal = (const float*)d_in[2];
    float* out = (float*)d_out;

    char* ws = (char*)d_ws;
    const size_t off_tbf     = 0;                        // 131072
    const size_t off_partial = 131072;                   // 512*128*5*8 = 2621440
    const size_t off_topidx  = off_partial + 2621440;    // 2560
    const size_t off_bkmask  = off_topidx + 2560;        // 40960

    unsigned int* t_bf = (unsigned int*)(ws + off_tbf);
    float2* partial = (float2*)(ws + off_partial);
    int* top_idx = (int*)(ws + off_topidx);
    unsigned long long* bkmask = (unsigned long long*)(ws + off_bkmask);

    hipLaunchKernelGGL(k0_cvt_t, dim3(B * D / 4 / 256), dim3(256), 0, stream, t_f, t_bf);
    hipLaunchKernelGGL(k1_sims, dim3(NBLK1), dim3(512), 0, stream,
                       (const unsigned short*)t_bf, gal, partial);
    hipLaunchKernelGGL(k2_merge, dim3(B), dim3(512), 0, stream, partial, top_idx);
    hipLaunchKernelGGL(k3_member, dim3(B * K), dim3(512), 0, stream, s_f, gal, top_idx, bkmask);
    hipLaunchKernelGGL(k4_final, dim3(1), dim3(512), 0, stream, bkmask, out);
}

// Round 18
// 91.522 us; speedup vs baseline: 1.6259x; 1.6259x over previous
//
#include <hip/hip_runtime.h>

#define B 128
#define N 65536
#define D 512
#define K 5
#define M 256              // D * RATIO
#define GPB 256            // gallery rows per block (kernel1)
#define NBLK1 (N / GPB)    // 256 blocks
#define CHR 16             // g-rows per chunk (full D each)
#define NCHK (GPB / CHR)   // 16

typedef __attribute__((ext_vector_type(8))) short short8;
typedef __attribute__((ext_vector_type(4))) float f32x4;
typedef __attribute__((address_space(1))) const unsigned char as1cu8;
typedef __attribute__((address_space(3))) unsigned char as3u8;

// pack two fp32 -> one u32 of 2 bf16 (truncation) via v_perm_b32.
__device__ __forceinline__ unsigned int pack_bf2(float lo, float hi) {
    return __builtin_amdgcn_perm(__float_as_uint(hi), __float_as_uint(lo), 0x07060302u);
}

__device__ __forceinline__ void top5_insert(float v, int gi, float tv[K], int ti[K]) {
    // descending by value, ties broken by lower index (matches lax.top_k)
    if (v > tv[K - 1] || (v == tv[K - 1] && gi < ti[K - 1])) {
        tv[K - 1] = v; ti[K - 1] = gi;
        #pragma unroll
        for (int k = K - 1; k > 0; --k) {
            bool sw = (tv[k] > tv[k - 1]) || (tv[k] == tv[k - 1] && ti[k] < ti[k - 1]);
            if (sw) {
                float fv = tv[k]; tv[k] = tv[k - 1]; tv[k - 1] = fv;
                int fi = ti[k]; ti[k] = ti[k - 1]; ti[k - 1] = fi;
            }
        }
    }
}

// packed-score insert (meta lives in low 8 mantissa bits; candidates distinct)
__device__ __forceinline__ void pk_insert(float sp, float lst[K]) {
    if (sp > lst[K - 1]) {
        lst[K - 1] = sp;
        #pragma unroll
        for (int k = K - 1; k > 0; --k)
            if (lst[k] > lst[k - 1]) {
                float t2 = lst[k]; lst[k] = lst[k - 1]; lst[k - 1] = t2;
            }
    }
}

// k1 (R12 configuration — best measured total, 125.7us): fp32 gallery via
// global_load_lds, 16 waves = (bt 0..7) x (kh 0..1), t-fragments 32 regs/wave,
// single __syncthreads per chunk, cross-k-half C exchange one chunk behind.
// Occupancy audit (R18): true per-wave regs (arch+acc unified file) ~130+ ->
// exactly 1 block/CU resident at 1024 thr; 16 waves/CU is this structure's
// ceiling, and k1 ~90us is its plateau.
__global__ __launch_bounds__(1024) void k1_sims(const float* __restrict__ t_f,
                                                const float* __restrict__ gal,
                                                float2* __restrict__ partial) {
    __shared__ __align__(16) char gbuf[2][CHR * 2048];   // 65536 B fp32 chunks
    __shared__ __align__(16) float cbuf_c[2][16][256];   // 32768 B C exchange
    __shared__ __align__(16) float cbuf_n[2][16][16];    //  2048 B norm exchange

    const int tid = threadIdx.x;
    const int blk = blockIdx.x;
    const int lane = tid & 63;
    const int w = tid >> 6;
    const int l15 = lane & 15;
    const int l4 = lane >> 4;
    const int bt = w & 7;     // b-tile (16 b-rows)
    const int kh = w >> 3;    // k-half (ks 0-7 / 8-15)

    const char* gal_b = reinterpret_cast<const char*>(gal);
    const size_t rowbase = ((size_t)blk * GPB) * (D * 4);
    const int lsw = (lane * 16) ^ ((w & 7) << 4);   // swizzled lane offset (row = w)

    // DMA chunk c into gbuf[bi]: wave w stages row w of the chunk (2KB = 2 insts)
    auto DMA = [&](int c, int bi) {
        const char* s0 = gal_b + rowbase + ((size_t)c * CHR + w) * (D * 4) + lsw;
        char* d = &gbuf[bi][w * 2048];
        __builtin_amdgcn_global_load_lds((as1cu8*)s0, (as3u8*)d, 16, 0, 0);
        __builtin_amdgcn_global_load_lds((as1cu8*)(s0 + 1024), (as3u8*)(d + 1024), 16, 0, 0);
    };

    DMA(0, 0);

    // t-fragments: lane holds t[bt*16 + l15][ks*32 + l4*8 .. +8], ks = kh*8+j
    short8 tfr[8];
    {
        const float* tp = t_f + (size_t)(bt * 16 + l15) * D + (kh * 8) * 32 + l4 * 8;
        #pragma unroll
        for (int j = 0; j < 8; ++j) {
            float4 a = *reinterpret_cast<const float4*>(tp + j * 32);
            float4 b = *reinterpret_cast<const float4*>(tp + j * 32 + 4);
            uint4 q;
            q.x = pack_bf2(a.x, a.y); q.y = pack_bf2(a.z, a.w);
            q.z = pack_bf2(b.x, b.y); q.w = pack_bf2(b.z, b.w);
            tfr[j] = *reinterpret_cast<short8*>(&q);
        }
    }

    float lst[K];
    #pragma unroll
    for (int k = 0; k < K; ++k) lst[k] = -1e30f;

    const int xr = (l15 & 7) << 4;
    __syncthreads();   // chunk 0 staged

    for (int c = 0; c < NCHK; ++c) {
        const int bi = c & 1;
        if (c + 1 < NCHK) DMA(c + 1, bi ^ 1);

        // finish previous chunk: sum k-halves, scale, insert (kh==1 waves)
        if (c > 0 && kh == 1) {
            const int pb = bi ^ 1;
            f32x4 c0 = *reinterpret_cast<const f32x4*>(&cbuf_c[pb][bt][lane * 4]);
            f32x4 c1 = *reinterpret_cast<const f32x4*>(&cbuf_c[pb][8 + bt][lane * 4]);
            float4 n0 = *reinterpret_cast<const float4*>(&cbuf_n[pb][bt][l4 * 4]);
            float4 n1 = *reinterpret_cast<const float4*>(&cbuf_n[pb][8 + bt][l4 * 4]);
            float nn[4] = {n0.x + n1.x, n0.y + n1.y, n0.z + n1.z, n0.w + n1.w};
            #pragma unroll
            for (int r = 0; r < 4; ++r) {
                float s = (c0[r] + c1[r]) * rsqrtf(fmaxf(nn[r], 1e-24f));
                unsigned meta = (unsigned)((c - 1) * CHR + l4 * 4 + r);
                float sp = __uint_as_float((__float_as_uint(s) & 0xFFFFFF00u) | meta);
                pk_insert(sp, lst);
            }
        }

        // compute chunk c: 8 k-slices (this wave's k-half)
        f32x4 acc = (f32x4)0.0f;
        float nrm = 0.0f;
        const char* gb = &gbuf[bi][0];
        #pragma unroll
        for (int j = 0; j < 8; ++j) {
            const int ks = kh * 8 + j;
            const int base = l15 * 2048 + ks * 128;
            float4 a0 = *reinterpret_cast<const float4*>(gb + base + ((l4 * 32) ^ xr));
            float4 a1 = *reinterpret_cast<const float4*>(gb + base + ((l4 * 32 + 16) ^ xr));
            nrm = fmaf(a0.x, a0.x, nrm); nrm = fmaf(a0.y, a0.y, nrm);
            nrm = fmaf(a0.z, a0.z, nrm); nrm = fmaf(a0.w, a0.w, nrm);
            nrm = fmaf(a1.x, a1.x, nrm); nrm = fmaf(a1.y, a1.y, nrm);
            nrm = fmaf(a1.z, a1.z, nrm); nrm = fmaf(a1.w, a1.w, nrm);
            uint4 q;
            q.x = pack_bf2(a0.x, a0.y); q.y = pack_bf2(a0.z, a0.w);
            q.z = pack_bf2(a1.x, a1.y); q.w = pack_bf2(a1.z, a1.w);
            short8 af = *reinterpret_cast<short8*>(&q);
            acc = __builtin_amdgcn_mfma_f32_16x16x32_bf16(af, tfr[j], acc, 0, 0, 0);
        }
        // half-row norms: sum over l4 quarters (this k-half)
        nrm += __shfl_xor(nrm, 16);
        nrm += __shfl_xor(nrm, 32);
        if (lane < CHR) cbuf_n[bi][w][lane] = nrm;
        *reinterpret_cast<f32x4*>(&cbuf_c[bi][w][lane * 4]) = acc;

        __syncthreads();   // cbuf visible + next chunk's DMA drained
    }

    // epilogue: finish chunk NCHK-1
    if (kh == 1) {
        const int pb = (NCHK - 1) & 1;
        f32x4 c0 = *reinterpret_cast<const f32x4*>(&cbuf_c[pb][bt][lane * 4]);
        f32x4 c1 = *reinterpret_cast<const f32x4*>(&cbuf_c[pb][8 + bt][lane * 4]);
        float4 n0 = *reinterpret_cast<const float4*>(&cbuf_n[pb][bt][l4 * 4]);
        float4 n1 = *reinterpret_cast<const float4*>(&cbuf_n[pb][8 + bt][l4 * 4]);
        float nn[4] = {n0.x + n1.x, n0.y + n1.y, n0.z + n1.z, n0.w + n1.w};
        #pragma unroll
        for (int r = 0; r < 4; ++r) {
            float s = (c0[r] + c1[r]) * rsqrtf(fmaxf(nn[r], 1e-24f));
            unsigned meta = (unsigned)((NCHK - 1) * CHR + l4 * 4 + r);
            float sp = __uint_as_float((__float_as_uint(s) & 0xFFFFFF00u) | meta);
            pk_insert(sp, lst);
        }
    }

    // merge per-b lists across the 4 l4 lanes (masks 16, 32)
    #pragma unroll
    for (int mk = 16; mk <= 32; mk <<= 1) {
        float inc[K];
        #pragma unroll
        for (int k = 0; k < K; ++k) inc[k] = __shfl_xor(lst[k], mk);
        #pragma unroll
        for (int k = 0; k < K; ++k) pk_insert(inc[k], lst);
    }

    if (kh == 1 && l4 == 0) {
        const int b = bt * 16 + l15;
        #pragma unroll
        for (int k = 0; k < K; ++k) {
            unsigned sp = __float_as_uint(lst[k]);
            int g = blk * GPB + (int)(sp & 0xFFu);
            partial[((size_t)b * NBLK1 + blk) * K + k] = make_float2(lst[k], __int_as_float(g));
        }
    }
}

// k2: merge 256 partial top-5 lists per batch row -> top_idx. Shuffle-first.
__global__ __launch_bounds__(512) void k2_merge(const float2* __restrict__ partial,
                                                int* __restrict__ top_idx) {
    __shared__ float2 wlist[8][K];
    const int b = blockIdx.x;
    const int p = threadIdx.x;
    const int lane = p & 63;
    const int w = p >> 6;

    float mv[K]; int mi[K];
    #pragma unroll
    for (int k = 0; k < K; ++k) { mv[k] = -1e30f; mi[k] = 0x7fffffff; }
    if (p < NBLK1) {
        #pragma unroll
        for (int k = 0; k < K; ++k) {
            float2 c = partial[((size_t)b * NBLK1 + p) * K + k];
            mv[k] = c.x; mi[k] = __float_as_int(c.y);
        }
    }
    #pragma unroll
    for (int mk = 1; mk <= 32; mk <<= 1) {
        float ov[K]; int oi[K];
        #pragma unroll
        for (int k = 0; k < K; ++k) { ov[k] = __shfl_xor(mv[k], mk); oi[k] = __shfl_xor(mi[k], mk); }
        #pragma unroll
        for (int k = 0; k < K; ++k) top5_insert(ov[k], oi[k], mv, mi);
    }
    if (lane == 0) {
        #pragma unroll
        for (int k = 0; k < K; ++k) wlist[w][k] = make_float2(mv[k], __int_as_float(mi[k]));
    }
    __syncthreads();
    if (w == 0) {
        #pragma unroll
        for (int k = 0; k < K; ++k) { mv[k] = -1e30f; mi[k] = 0x7fffffff; }
        if (lane < 8) {
            #pragma unroll
            for (int k = 0; k < K; ++k) {
                float2 c = wlist[lane][k];
                mv[k] = c.x; mi[k] = __float_as_int(c.y);
            }
        }
        #pragma unroll
        for (int mk = 1; mk <= 4; mk <<= 1) {
            float ov[K]; int oi[K];
            #pragma unroll
            for (int k = 0; k < K; ++k) { ov[k] = __shfl_xor(mv[k], mk); oi[k] = __shfl_xor(mi[k], mk); }
            #pragma unroll
            for (int k = 0; k < K; ++k) top5_insert(ov[k], oi[k], mv, mi);
        }
        if (lane == 0) {
            #pragma unroll
            for (int k = 0; k < K; ++k) top_idx[b * K + k] = mi[k];
        }
    }
}

// k3: one block per (b,k) row: bottom-m membership of |gal[row,c]*s_f[b,c]|
// (per-row norms are positive constants -> ordering matches the reference's
// normalized products). Plain stores; kernel-boundary coherence (R8 lesson).
__global__ __launch_bounds__(512) void k3_member(const float* __restrict__ s_f,
                                                 const float* __restrict__ gal,
                                                 const int* __restrict__ top_idx,
                                                 unsigned long long* __restrict__ bkmask) {
    __shared__ __align__(16) float pS[D];
    const int p = threadIdx.x;
    const int bk = blockIdx.x;
    const int b = bk / K;
    const int row = top_idx[bk];
    float pv = fabsf(gal[(size_t)row * D + p] * s_f[(size_t)b * D + p]);
    pS[p] = pv;
    __syncthreads();
    int cnt = 0;
    const float4* p4 = reinterpret_cast<const float4*>(pS);
    #pragma unroll 4
    for (int j = 0; j < D / 4; ++j) {
        float4 o = p4[j];
        cnt += (o.x < pv || (o.x == pv && (4 * j + 0) < p)) ? 1 : 0;
        cnt += (o.y < pv || (o.y == pv && (4 * j + 1) < p)) ? 1 : 0;
        cnt += (o.z < pv || (o.z == pv && (4 * j + 2) < p)) ? 1 : 0;
        cnt += (o.w < pv || (o.w == pv && (4 * j + 3) < p)) ? 1 : 0;
    }
    unsigned long long bm = __ballot(cnt < M);
    if ((p & 63) == 0) bkmask[(size_t)bk * 8 + (p >> 6)] = bm;
}

// k4: parallel AND-reduce of the 640 per-(b,k) masks (R18: replaces the
// serial 160-iteration loop — latency-chained single-block scan was ~10us).
// Stage 1: 512 threads each AND 10 masks for (seg, word). Stage 2: each
// output channel ANDs its word across the 64 segments from LDS.
__global__ __launch_bounds__(512) void k4_final(const unsigned long long* __restrict__ bkmask,
                                                float* __restrict__ out) {
    __shared__ unsigned long long red[64][8];
    const int t = threadIdx.x;
    {
        const int word = t & 7, seg = t >> 3;   // seg 0..63
        unsigned long long acc = ~0ull;
        #pragma unroll
        for (int i = 0; i < 10; ++i)
            acc &= bkmask[(size_t)(seg * 10 + i) * 8 + word];
        red[seg][word] = acc;
    }
    __syncthreads();
    const int word = t >> 6, bit = t & 63;
    unsigned long long m = ~0ull;
    #pragma unroll 8
    for (int seg = 0; seg < 64; ++seg) m &= red[seg][word];
    out[t] = ((m >> bit) & 1ull) ? 0.0f : 1.0f;
}

extern "C" void kernel_launch(void* const* d_in, const int* in_sizes, int n_in,
                              void* d_out, int out_size, void* d_ws, size_t ws_size,
                              hipStream_t stream) {
    (void)in_sizes; (void)n_in; (void)out_size; (void)ws_size;
    const float* s_f = (const float*)d_in[0];
    const float* t_f = (const float*)d_in[1];
    const float* gal = (const float*)d_in[2];
    float* out = (float*)d_out;

    char* ws = (char*)d_ws;
    const size_t off_partial = 0;                        // 128*256*5*8 = 1310720
    const size_t off_topidx  = off_partial + 1310720;    // 2560
    const size_t off_bkmask  = off_topidx + 2560;        // 40960

    float2* partial = (float2*)(ws + off_partial);
    int* top_idx = (int*)(ws + off_topidx);
    unsigned long long* bkmask = (unsigned long long*)(ws + off_bkmask);

    hipLaunchKernelGGL(k1_sims, dim3(NBLK1), dim3(1024), 0, stream, t_f, gal, partial);
    hipLaunchKernelGGL(k2_merge, dim3(B), dim3(512), 0, stream, partial, top_idx);
    hipLaunchKernelGGL(k3_member, dim3(B * K), dim3(512), 0, stream, s_f, gal, top_idx, bkmask);
    hipLaunchKernelGGL(k4_final, dim3(1), dim3(512), 0, stream, bkmask, out);
}